// Round 11
// baseline (647.249 us; speedup 1.0000x reference)
//
#include <hip/hip_runtime.h>
#include <hip/hip_bf16.h>

typedef unsigned short bf16;  // raw bf16 bit pattern
typedef short s16x8 __attribute__((ext_vector_type(8)));
typedef float f32x4 __attribute__((ext_vector_type(4)));

#define D_  768
#define FF_ 3072
#define H_  12
#define B_  2
#define S_  1025
#define M_  8
#define SP  1056      // padded score row length (16B-aligned rows)
#define NS  2050      // B_*S_
#define NMS 16400     // B_*M_*S_
#define NALL 18450    // NS + NMS
#define MPAD 18688    // 73*256
#define QKVN 2304     // 3*D_

__device__ __forceinline__ float b2f(bf16 u){ return __uint_as_float(((unsigned int)u) << 16); }
__device__ __forceinline__ bf16 f2b(float f){
    unsigned int b = __float_as_uint(f);
    unsigned int lsb = (b >> 16) & 1u;
    b += 0x7fffu + lsb;            // round-to-nearest-even
    return (bf16)(b >> 16);
}

// async global->LDS, 16B per lane. LDS dest = wave-uniform base + lane*16.
typedef __attribute__((address_space(1))) const void gvoid;
typedef __attribute__((address_space(3))) void lvoid;
__device__ __forceinline__ void gload16(const void* g, void* l){
    __builtin_amdgcn_global_load_lds((gvoid*)(unsigned long long)g,
        (lvoid*)(unsigned int)(unsigned long long)l, 16, 0, 0);
}

// bijective XCD swizzle (m204): contiguous work chunks per XCD
__device__ __forceinline__ int xcd_swz(int flat, int nwg){
    int q = nwg >> 3, r = nwg & 7;
    int xcd = flat & 7, slot = flat >> 3;
    int base = (xcd < r) ? xcd * (q + 1) : r * (q + 1) + (xcd - r) * q;
    return base + slot;
}

// ---------------- LayerNorm: f32 in -> bf16 out (+ optional f32 out) ----------------
__global__ __launch_bounds__(256) void ln_kernel(const float* __restrict__ in,
        const float* __restrict__ g, const float* __restrict__ be,
        bf16* __restrict__ out_bf, float* __restrict__ out_f32)
{
    int row = blockIdx.x;
    const float* r = in + (size_t)row * D_;
    int t = threadIdx.x;
    float v0 = r[t], v1 = r[t + 256], v2 = r[t + 512];
    float s  = v0 + v1 + v2;
    float ss = v0*v0 + v1*v1 + v2*v2;
    for (int o = 32; o; o >>= 1){ s += __shfl_xor(s, o); ss += __shfl_xor(ss, o); }
    __shared__ float sA[4], sB[4];
    int wid = t >> 6, lane = t & 63;
    if (lane == 0){ sA[wid] = s; sB[wid] = ss; }
    __syncthreads();
    s  = sA[0] + sA[1] + sA[2] + sA[3];
    ss = sB[0] + sB[1] + sB[2] + sB[3];
    float mean = s * (1.f / D_);
    float var  = ss * (1.f / D_) - mean * mean;
    float rstd = rsqrtf(var + 1e-6f);
    float vs[3] = {v0, v1, v2};
    #pragma unroll
    for (int i = 0; i < 3; i++){
        int c = t + i * 256;
        float y = (vs[i] - mean) * rstd * g[c] + be[c];
        out_bf[(size_t)row * D_ + c] = f2b(y);
        if (out_f32) out_f32[(size_t)row * D_ + c] = y;
    }
}

// ---------------- weight transpose f32 [K][N] -> bf16 [N][K] ----------------
__global__ __launch_bounds__(256) void transpose_w(const float* __restrict__ W,
        bf16* __restrict__ WT, int K, int N)
{
    __shared__ float tile[32][33];
    int n0 = blockIdx.x * 32, k0 = blockIdx.y * 32;
    int tx = threadIdx.x & 31, ty = threadIdx.x >> 5;
    #pragma unroll
    for (int i = 0; i < 4; i++)
        tile[ty + i*8][tx] = W[(size_t)(k0 + ty + i*8) * N + n0 + tx];
    __syncthreads();
    #pragma unroll
    for (int i = 0; i < 4; i++)
        WT[(size_t)(n0 + ty + i*8) * K + k0 + tx] = f2b(tile[tx][ty + i*8]);
}

// ---------------- v (qkv col 1536+) [B,S,2304] -> vT [B,D,SP] bf16 ----------------
__global__ __launch_bounds__(256) void transpose_v(const bf16* __restrict__ qkv,
        bf16* __restrict__ vT)
{
    __shared__ bf16 tile[32][33];
    int c0 = blockIdx.x * 32, s0 = blockIdx.y * 32, b = blockIdx.z;
    int tx = threadIdx.x & 31, ty = threadIdx.x >> 5;
    #pragma unroll
    for (int i = 0; i < 4; i++){
        int s = s0 + ty + i*8;
        tile[ty + i*8][tx] = (s < S_) ? qkv[((size_t)b * S_ + s) * QKVN + 1536 + c0 + tx] : (bf16)0;
    }
    __syncthreads();
    #pragma unroll
    for (int i = 0; i < 4; i++){
        int c = c0 + ty + i*8, s = s0 + tx;
        vT[((size_t)b * D_ + c) * SP + s] = tile[tx][ty + i*8];
    }
}

// ---------------- fused row-max + E = exp(s - max) in place; pads -> 0 ----------------
__global__ __launch_bounds__(256) void softexp(bf16* __restrict__ sc, int nrows)
{
    int wid = threadIdx.x >> 6, lane = threadIdx.x & 63;
    int row = blockIdx.x * 4 + wid;
    if (row >= nrows) return;
    bf16* srow = sc + (size_t)row * SP;
    s16x8 v0 = *(s16x8*)(srow + lane * 8);
    s16x8 v1 = *(s16x8*)(srow + 512 + lane * 8);
    s16x8 v2 = {0,0,0,0,0,0,0,0};
    if (lane < 4) v2 = *(s16x8*)(srow + 1024 + lane * 8);
    float m = -1e30f;
    #pragma unroll
    for (int e = 0; e < 8; e++) m = fmaxf(m, b2f((bf16)v0[e]));
    #pragma unroll
    for (int e = 0; e < 8; e++) m = fmaxf(m, b2f((bf16)v1[e]));
    if (lane == 0) m = fmaxf(m, b2f((bf16)v2[0]));
    for (int o = 32; o; o >>= 1) m = fmaxf(m, __shfl_xor(m, o));
    s16x8 o0, o1, o2;
    #pragma unroll
    for (int e = 0; e < 8; e++) o0[e] = (short)f2b(__expf(b2f((bf16)v0[e]) - m));
    #pragma unroll
    for (int e = 0; e < 8; e++) o1[e] = (short)f2b(__expf(b2f((bf16)v1[e]) - m));
    #pragma unroll
    for (int e = 0; e < 8; e++){
        int col = 1024 + lane * 8 + e;
        o2[e] = (col < S_) ? (short)f2b(__expf(b2f((bf16)v2[e]) - m)) : (short)0;
    }
    *(s16x8*)(srow + lane * 8) = o0;
    *(s16x8*)(srow + 512 + lane * 8) = o1;
    if (lane < 4) *(s16x8*)(srow + 1024 + lane * 8) = o2;
}

// ---------------- pack masks into per-(b,m) col bitmask (132 bytes) ----------------
__global__ void pack_masks(const int* __restrict__ masks, unsigned char* __restrict__ mpk)
{
    int g = blockIdx.x;
    int i = threadIdx.x;
    unsigned char v = 0;
    for (int j = 0; j < 8; j++){
        int col = i * 8 + j;
        if (col >= 1 && col <= 1024 && masks[(size_t)g * 1024 + col - 1] != 0) v |= (1 << j);
    }
    mpk[g * 132 + i] = v;
}

// ---------------- concat qkv bias ----------------
__global__ void cat_bias(const float* __restrict__ a, const float* __restrict__ b,
        const float* __restrict__ c, float* __restrict__ o)
{
    int i = blockIdx.x * 256 + threadIdx.x;
    if (i >= QKVN) return;
    o[i] = (i < 768) ? a[i] : (i < 1536 ? b[i - 768] : c[i - 1536]);
}

// ---------------- PV: (E [⊙mask]) @ V, dbuf staging, denom in-kernel ----------------
template<bool MASKED>
__global__ __launch_bounds__(256) void pv_kernel(const bf16* __restrict__ E,
        const bf16* __restrict__ vT, const unsigned char* __restrict__ mpk,
        bf16* __restrict__ out)
{
    __shared__ __align__(16) bf16 Ps[2][2048];
    __shared__ __align__(16) bf16 Vs[2][2048];
    __shared__ unsigned char mbytes[136];
    __shared__ float dinv[64];
    int h, g, b, q0;
    if (MASKED){
        int work = xcd_swz(blockIdx.x, 17 * B_ * M_ * H_);
        int m = work & 7; int rest = work >> 3;
        int q0b = rest % 17; int zbh = rest / 17;
        b = zbh / H_; h = zbh % H_;
        g = b * M_ + m;
        q0 = q0b * 64;
    } else {
        int z = blockIdx.y; h = z % H_; g = z / H_; b = g;
        q0 = blockIdx.x * 64;
    }
    bool fullq = (q0 + 64 <= S_);
    int t = threadIdx.x, w = t >> 6, l = t & 63;
    if (MASKED && t < 132) mbytes[t] = mpk[g * 132 + t];
    int row_l = t >> 2;
    int gch = (t & 3) ^ ((t >> 3) & 3);
    const bf16* gP = E + ((size_t)(b * H_ + h) * S_ + q0 + row_l) * SP + gch * 8;
    const bf16* gV = vT + ((size_t)b * D_ + h * 64 + row_l) * SP + gch * 8;
    int lr = l & 15;
    int lc = l >> 4;
    int ca = lc ^ ((lr >> 1) & 3);
    f32x4 acc[4];
    #pragma unroll
    for (int n = 0; n < 4; n++){ acc[n][0]=0.f; acc[n][1]=0.f; acc[n][2]=0.f; acc[n][3]=0.f; }
    float dsum = 0.f;
    bf16 *Pc = Ps[0], *Pa = Ps[1], *Vc = Vs[0], *Va = Vs[1];
    auto stage = [&](int k0, bf16* Pd, bf16* Vd){
        gload16(gV + k0, Vd + w * 512);
        if (fullq) gload16(gP + k0, Pd + w * 512);
        else {
            s16x8 p = {0,0,0,0,0,0,0,0};
            if (q0 + row_l < S_) p = *(const s16x8*)(gP + k0);
            *(s16x8*)&Pd[row_l * 32 + (t & 3) * 8] = p;
        }
    };
    stage(0, Pc, Vc);
    __syncthreads();
    for (int it = 0; it < 33; ++it){
        if (it < 32) stage(it * 32 + 32, Pa, Va);
        s16x8 a = *(s16x8*)&Pc[(w * 16 + lr) * 32 + ca * 8];
        if (MASKED){
            int mb = mbytes[it * 4 + lc];
            #pragma unroll
            for (int j = 0; j < 8; j++) if (!((mb >> j) & 1)) a[j] = 0;
        }
        #pragma unroll
        for (int j = 0; j < 8; j++) dsum += b2f((bf16)a[j]);
        #pragma unroll
        for (int n = 0; n < 4; n++){
            s16x8 bb = *(s16x8*)&Vc[(n * 16 + lr) * 32 + ca * 8];
            acc[n] = __builtin_amdgcn_mfma_f32_16x16x32_bf16(a, bb, acc[n], 0, 0, 0);
        }
        __syncthreads();
        bf16* tp;
        tp = Pc; Pc = Pa; Pa = tp;
        tp = Vc; Vc = Va; Va = tp;
    }
    dsum += __shfl_xor(dsum, 16);
    dsum += __shfl_xor(dsum, 32);
    if (l < 16) dinv[w * 16 + l] = 1.f / dsum;
    __syncthreads();
    int qb = q0 + w * 16 + (l >> 4) * 4;
    #pragma unroll
    for (int n = 0; n < 4; n++)
        #pragma unroll
        for (int e = 0; e < 4; e++){
            int qq = qb + e;
            if (qq < S_){
                float inv = dinv[w * 16 + (l >> 4) * 4 + e];
                out[((size_t)g * S_ + qq) * D_ + h * 64 + n * 16 + lr] = f2b(acc[n][e] * inv);
            }
        }
}

// ---------------- 2-phase NT GEMM (QKV + scores only) ----------------
#define GBM 128
#define GBK 32

template<int BN, int OUTBF, int RESM, int DOGELU>
__global__ __launch_bounds__(512, BN == 128 ? 6 : 4) void gemm_nt(
        const bf16* __restrict__ A, const bf16* __restrict__ Bt,
        const float* __restrict__ bias, const float* __restrict__ res,
        const float* __restrict__ res2,
        void* __restrict__ Cp,
        int Mm, int Nn, int Kk, int lda, int ldb, int ldc,
        float scale, int ZH,
        long a_z1, long a_z2, long b_z1, long b_z2, long c_z1, long c_z2)
{
    constexpr int NF = BN / 64;
    __shared__ __align__(16) bf16 As[3][GBM * GBK];
    __shared__ __align__(16) bf16 Bs[3][BN * GBK];
    int z = blockIdx.z;
    int z1 = z / ZH, z2 = z % ZH;
    const bf16* Ab = A + z1 * a_z1 + z2 * a_z2;
    const bf16* Bb = Bt + z1 * b_z1 + z2 * b_z2;
    size_t c_off = (size_t)(z1 * c_z1 + z2 * c_z2);
    int gx = gridDim.x, gy = gridDim.y;
    int flat = blockIdx.y * gx + blockIdx.x;
    int work = xcd_swz(flat, gx * gy);
    int m0 = (work / gy) * GBM, n0 = (work % gy) * BN;
    int t = threadIdx.x, w = t >> 6, l = t & 63;
    int wm = (w >> 2) * 64, wn = (w & 3) * (BN / 4);
    int lr = l & 15;
    int ca = (l >> 4) ^ ((lr >> 1) & 3);
    int srow = t >> 2;
    int gch = (t & 3) ^ ((t >> 3) & 3);
    bool full = (m0 + GBM <= Mm) && (n0 + BN <= Nn);
    const bf16* gA = Ab + (size_t)(m0 + srow) * lda + gch * 8;
    const bf16* gB = Bb + (size_t)(n0 + srow) * ldb + gch * 8;
    const bf16* gB2 = gB + (size_t)128 * ldb;
    f32x4 acc[4][NF];
    #pragma unroll
    for (int i = 0; i < 4; i++)
        #pragma unroll
        for (int j = 0; j < NF; j++){ acc[i][j][0]=0.f; acc[i][j][1]=0.f; acc[i][j][2]=0.f; acc[i][j][3]=0.f; }

    int nt = Kk >> 5;
    auto compute = [&](const bf16* Ac, const bf16* Bc){
        s16x8 af[4], bfr[NF];
        #pragma unroll
        for (int i = 0; i < 4; i++) af[i] = *(const s16x8*)&Ac[(wm + i * 16 + lr) * 32 + ca * 8];
        #pragma unroll
        for (int j = 0; j < NF; j++) bfr[j] = *(const s16x8*)&Bc[(wn + j * 16 + lr) * 32 + ca * 8];
        #pragma unroll
        for (int i = 0; i < 4; i++)
            #pragma unroll
            for (int j = 0; j < NF; j++)
                acc[i][j] = __builtin_amdgcn_mfma_f32_16x16x32_bf16(af[i], bfr[j], acc[i][j], 0, 0, 0);
    };

    if (full){
        auto stage = [&](int k0, bf16* Ad, bf16* Bd){
            gload16(gA + k0, Ad + w * 512);
            gload16(gB + k0, Bd + w * 512);
            if constexpr (BN == 256) gload16(gB2 + k0, Bd + 4096 + w * 512);
        };
        stage(0, As[0], Bs[0]);
        if (nt > 1) stage(32, As[1], Bs[1]);
        __syncthreads();
        for (int it = 0; it < nt; ++it){
            int ib = it % 3;
            if (it + 2 < nt){
                stage((it + 2) << 5, As[(it + 2) % 3], Bs[(it + 2) % 3]);
                if constexpr (BN == 256) asm volatile("s_waitcnt vmcnt(6)" ::: "memory");
                else                     asm volatile("s_waitcnt vmcnt(4)" ::: "memory");
            } else if (it + 1 < nt){
                if constexpr (BN == 256) asm volatile("s_waitcnt vmcnt(3)" ::: "memory");
                else                     asm volatile("s_waitcnt vmcnt(2)" ::: "memory");
            } else {
                asm volatile("s_waitcnt vmcnt(0)" ::: "memory");
            }
            __builtin_amdgcn_sched_barrier(0);
            __builtin_amdgcn_s_barrier();
            __builtin_amdgcn_sched_barrier(0);
            compute(As[ib], Bs[ib]);
            __builtin_amdgcn_sched_barrier(0);
            __builtin_amdgcn_s_barrier();
        }
    } else {
        auto stage_e = [&](int k0, bf16* Ad, bf16* Bd){
            s16x8 z8 = {0,0,0,0,0,0,0,0};
            s16x8 va = z8; if (m0 + srow < Mm) va = *(const s16x8*)(gA + k0);
            *(s16x8*)&Ad[srow * 32 + (t & 3) * 8] = va;
            s16x8 vb = z8; if (n0 + srow < Nn) vb = *(const s16x8*)(gB + k0);
            *(s16x8*)&Bd[srow * 32 + (t & 3) * 8] = vb;
            if constexpr (BN == 256){
                s16x8 vc = z8; if (n0 + srow + 128 < Nn) vc = *(const s16x8*)(gB2 + k0);
                *(s16x8*)&Bd[(srow + 128) * 32 + (t & 3) * 8] = vc;
            }
        };
        bf16 *Ac = As[0], *Aa = As[1], *Bc = Bs[0], *Ba = Bs[1];
        stage_e(0, Ac, Bc);
        __syncthreads();
        for (int it = 0; it < nt; ++it){
            if (it + 1 < nt) stage_e((it + 1) << 5, Aa, Ba);
            compute(Ac, Bc);
            __syncthreads();
            bf16* tp;
            tp = Ac; Ac = Aa; Aa = tp;
            tp = Bc; Bc = Ba; Ba = tp;
        }
    }

    #pragma unroll
    for (int i = 0; i < 4; i++)
        #pragma unroll
        for (int j = 0; j < NF; j++)
            #pragma unroll
            for (int e = 0; e < 4; e++){
                int rr = m0 + wm + i * 16 + (l >> 4) * 4 + e;
                int cc = n0 + wn + j * 16 + lr;
                if (rr < Mm && cc < Nn){
                    float v = acc[i][j][e] * scale;
                    if (bias) v += bias[cc];
                    if (DOGELU) v = 0.5f * v * (1.f + erff(v * 0.70710678118654752f));
                    if (RESM == 1) v += res[(size_t)rr * 768 + cc];
                    if (OUTBF) ((bf16*)Cp)[c_off + (size_t)rr * ldc + cc] = f2b(v);
                    else       ((float*)Cp)[c_off + (size_t)rr * ldc + cc] = v;
                }
            }
}

// ---------------- 8-phase 256x256 NT GEMM (Wp / W1 / W2) ----------------
// BK=64, 8 waves; wave out = rows {(w>>2)*64 + mh*128} x cols {(w&3)*32 + nh*128}.
// LDS 2 bufs x (A 32KB + B 32KB) = 128KB. Bank swizzle: phys_chunk = c ^ (row&7).
// Template-exact schedule (m201): no sched_barrier except after lgkmcnt(0) (rule 18);
// counted vmcnt(4) at phases 1,2,4 only; setprio around MFMA clusters.
#define LGKM0 asm volatile("s_waitcnt lgkmcnt(0)" ::: "memory"); __builtin_amdgcn_sched_barrier(0);
#define VM4   asm volatile("s_waitcnt vmcnt(4)" ::: "memory");
#define READ_A8(MH, SRC) \
    _Pragma("unroll") for (int mi = 0; mi < 4; mi++){ \
        af[mi*2]   = *(const s16x8*)&SRC[((MH)*128 + wmr + mi*16)*64 + pc0]; \
        af[mi*2+1] = *(const s16x8*)&SRC[((MH)*128 + wmr + mi*16)*64 + pc1]; }
#define READ_B8(NH, SRC, DST) \
    _Pragma("unroll") for (int nj = 0; nj < 2; nj++){ \
        DST[nj*2]   = *(const s16x8*)&SRC[((NH)*128 + wnr + nj*16)*64 + pc0]; \
        DST[nj*2+1] = *(const s16x8*)&SRC[((NH)*128 + wnr + nj*16)*64 + pc1]; }
#define MFMA16(MH, NH, BF) \
    __builtin_amdgcn_s_setprio(1); \
    _Pragma("unroll") for (int mi = 0; mi < 4; mi++) \
        _Pragma("unroll") for (int nj = 0; nj < 2; nj++){ \
            acc[(MH)*4+mi][(NH)*2+nj] = __builtin_amdgcn_mfma_f32_16x16x32_bf16(af[mi*2],   BF[nj*2],   acc[(MH)*4+mi][(NH)*2+nj], 0,0,0); \
            acc[(MH)*4+mi][(NH)*2+nj] = __builtin_amdgcn_mfma_f32_16x16x32_bf16(af[mi*2+1], BF[nj*2+1], acc[(MH)*4+mi][(NH)*2+nj], 0,0,0); } \
    __builtin_amdgcn_s_setprio(0);
#define STAGE_A8(MH, K0, DB) \
    gload16(pA + (size_t)((MH)*128)*lda + (K0), (DB) + (MH)*8192 + w*512); \
    gload16(pA + (size_t)((MH)*128+64)*lda + (K0), (DB) + (MH)*8192 + 4096 + w*512);
#define STAGE_B8(NH, K0, DB) \
    gload16(pB + (size_t)((NH)*128)*ldb + (K0), (DB) + (NH)*8192 + w*512); \
    gload16(pB + (size_t)((NH)*128+64)*ldb + (K0), (DB) + (NH)*8192 + 4096 + w*512);

template<int OUTBF, int RESM, int DOGELU>
__global__ __launch_bounds__(512, 1) void gemm8p(
        const bf16* __restrict__ A, const bf16* __restrict__ Bt,
        const float* __restrict__ bias, const float* __restrict__ res,
        const float* __restrict__ res2,
        void* __restrict__ Cp,
        int Mreal, int Nn, int Kk, int lda, int ldb, int ldc, float scale)
{
    __shared__ __align__(16) bf16 AS[2][16384];
    __shared__ __align__(16) bf16 BS[2][16384];
    int gx = gridDim.x, gy = gridDim.y;
    int flat = blockIdx.y * gx + blockIdx.x;
    int work = xcd_swz(flat, gx * gy);
    int m0 = (work / gy) * 256, n0 = (work % gy) * 256;
    int t = threadIdx.x, w = t >> 6, l = t & 63;
    int lr = l & 15, cq = l >> 4, eL = l & 7;
    int wmr = (w >> 2) * 64 + lr;              // A row within half
    int wnr = (w & 3) * 32 + lr;               // B row within half
    int pc0 = (cq ^ eL) * 8;                   // swizzled chunk offsets (elements)
    int pc1 = ((4 | cq) ^ eL) * 8;
    int cS = (l & 7) ^ ((l >> 3) & 7);         // stage source chunk
    const bf16* pA = A + (size_t)(m0 + w * 8 + (l >> 3)) * lda + cS * 8;
    const bf16* pB = Bt + (size_t)(n0 + w * 8 + (l >> 3)) * ldb + cS * 8;

    f32x4 acc[8][4];
    #pragma unroll
    for (int i = 0; i < 8; i++)
        #pragma unroll
        for (int j = 0; j < 4; j++){ acc[i][j][0]=0.f; acc[i][j][1]=0.f; acc[i][j][2]=0.f; acc[i][j][3]=0.f; }

    int nt = Kk >> 6;
    // prologue: tile 0 fully into buf 0
    STAGE_A8(0, 0, AS[0]); STAGE_B8(0, 0, BS[0]); STAGE_B8(1, 0, BS[0]); STAGE_A8(1, 0, AS[0]);
    asm volatile("s_waitcnt vmcnt(0)" ::: "memory");
    __syncthreads();

    s16x8 af[8], bf0[4], bf1[4];
    for (int tau = 0; tau < nt; ++tau){
        const bf16* Ac = AS[tau & 1];
        const bf16* Bc = BS[tau & 1];
        bf16* An = AS[(tau + 1) & 1];
        bf16* Bn = BS[(tau + 1) & 1];
        int k1 = (tau + 1) << 6;
        bool st = (tau + 1 < nt);
        // P1 (mh0,nh0): read A0,B0; stage A0'
        READ_A8(0, Ac); READ_B8(0, Bc, bf0);
        if (st){ STAGE_A8(0, k1, An); }
        __builtin_amdgcn_s_barrier();
        LGKM0
        MFMA16(0, 0, bf0);
        VM4
        __builtin_amdgcn_s_barrier();
        // P2 (mh0,nh1): read B1; stage B0'
        READ_B8(1, Bc, bf1);
        if (st){ STAGE_B8(0, k1, Bn); }
        __builtin_amdgcn_s_barrier();
        LGKM0
        MFMA16(0, 1, bf1);
        VM4
        __builtin_amdgcn_s_barrier();
        // P3 (mh1,nh1): read A1; stage B1'
        READ_A8(1, Ac);
        if (st){ STAGE_B8(1, k1, Bn); }
        __builtin_amdgcn_s_barrier();
        LGKM0
        MFMA16(1, 1, bf1);
        __builtin_amdgcn_s_barrier();
        // P4 (mh1,nh0): no reads (af=A1, bf0=B0 live); stage A1'
        if (st){ STAGE_A8(1, k1, An); }
        __builtin_amdgcn_s_barrier();
        MFMA16(1, 0, bf0);
        VM4
        __builtin_amdgcn_s_barrier();
    }

    #pragma unroll
    for (int i = 0; i < 8; i++)
        #pragma unroll
        for (int j = 0; j < 4; j++)
            #pragma unroll
            for (int e = 0; e < 4; e++){
                int rr = m0 + (i >> 2) * 128 + (w >> 2) * 64 + (i & 3) * 16 + (l >> 4) * 4 + e;
                int cc = n0 + (j >> 1) * 128 + (w & 3) * 32 + (j & 1) * 16 + lr;
                if (rr < Mreal){
                    float v = acc[i][j][e] * scale;
                    if (bias) v += bias[cc];
                    if (DOGELU) v = 0.5f * v * (1.f + erff(v * 0.70710678118654752f));
                    if (RESM == 1) v += res[(size_t)rr * 768 + cc];
                    else if (RESM == 3){
                        if (rr < NS) v += res[(size_t)rr * 768 + cc];
                        else {
                            int mr = rr - NS;
                            int rb = mr / 8200, rs = mr % 1025;
                            v += res2[((size_t)rb * 1025 + rs) * 768 + cc];
                        }
                    }
                    if (OUTBF) ((bf16*)Cp)[(size_t)rr * ldc + cc] = f2b(v);
                    else       ((float*)Cp)[(size_t)rr * ldc + cc] = v;
                }
            }
}

__global__ void write_idx(float* o){ o[threadIdx.x] = (float)(threadIdx.x >> 3); }

// =============================== host ===============================
extern "C" void kernel_launch(void* const* d_in, const int* in_sizes, int n_in,
                              void* d_out, int out_size, void* d_ws, size_t ws_size,
                              hipStream_t stream)
{
    const float* x    = (const float*)d_in[0];
    const int*   masks= (const int*)d_in[1];
    const float* Wq = (const float*)d_in[2];
    const float* bq = (const float*)d_in[3];
    const float* Wk = (const float*)d_in[4];
    const float* bk = (const float*)d_in[5];
    const float* Wv = (const float*)d_in[6];
    const float* bv = (const float*)d_in[7];
    const float* Wp = (const float*)d_in[8];
    const float* bp = (const float*)d_in[9];
    const float* W1 = (const float*)d_in[10];
    const float* b1 = (const float*)d_in[11];
    const float* W2 = (const float*)d_in[12];
    const float* b2 = (const float*)d_in[13];
    const float* g1  = (const float*)d_in[14];
    const float* be1 = (const float*)d_in[15];
    const float* g2  = (const float*)d_in[16];
    const float* be2 = (const float*)d_in[17];
    float* out = (float*)d_out;

    char* ws = (char*)d_ws;
    size_t off = 0;
    auto alloc = [&](size_t bytes)->char* {
        char* p = ws + off;
        off = (off + bytes + 255) & ~(size_t)255;
        return p;
    };
    // persistent through FFN
    bf16*  W1T   = (bf16*) alloc((size_t)FF_ * D_ * 2);
    bf16*  W2T   = (bf16*) alloc((size_t)D_ * FF_ * 2);
    float* x_all_pre = (float*)alloc((size_t)NALL * D_ * 4);   // main 0..2049 | masked 2050..
    bf16*  xn_all    = (bf16*) alloc((size_t)MPAD * D_ * 2);   // padded rows (garbage ok)
    // POOL: everything dead by FFN time; t_buf (MPAD x FF) overlays it
    size_t pool_need = (size_t)MPAD * FF_ * 2;                 // 114.8 MB
    char* pool = alloc(pool_need);
    size_t poff = 0;
    auto palloc = [&](size_t bytes)->char* {
        char* p = pool + poff;
        poff = (poff + bytes + 255) & ~(size_t)255;
        return p;
    };
    float* xn_f  = (float*)palloc((size_t)NS * D_ * 4);
    bf16*  xn_b  = (bf16*) palloc((size_t)NS * D_ * 2);
    bf16*  WqkvT = (bf16*) palloc((size_t)QKVN * D_ * 2);
    float* bqkv  = (float*)palloc((size_t)QKVN * 4);
    bf16*  WpT   = (bf16*) palloc((size_t)D_ * D_ * 2);
    bf16*  qkv   = (bf16*) palloc((size_t)NS * QKVN * 2);
    bf16*  sc    = (bf16*) palloc((size_t)B_ * H_ * S_ * SP * 2);   // scores -> E
    bf16*  vT    = (bf16*) palloc((size_t)B_ * D_ * SP * 2);
    unsigned char* mpk = (unsigned char*)palloc(16 * 132);
    bf16*  h_all = (bf16*) palloc((size_t)MPAD * D_ * 2);           // padded PV out
    bf16*  t_buf = (bf16*)pool;    // valid only after all POOL members are dead

    // 1. weight transposes + mask pack + bias concat
    transpose_w<<<dim3(D_/32, D_/32), 256, 0, stream>>>(Wq, WqkvT, D_, D_);
    transpose_w<<<dim3(D_/32, D_/32), 256, 0, stream>>>(Wk, WqkvT + (size_t)768*768, D_, D_);
    transpose_w<<<dim3(D_/32, D_/32), 256, 0, stream>>>(Wv, WqkvT + (size_t)1536*768, D_, D_);
    transpose_w<<<dim3(D_/32, D_/32), 256, 0, stream>>>(Wp, WpT, D_, D_);
    transpose_w<<<dim3(FF_/32, D_/32), 256, 0, stream>>>(W1, W1T, D_, FF_);
    transpose_w<<<dim3(D_/32, FF_/32), 256, 0, stream>>>(W2, W2T, FF_, D_);
    pack_masks<<<16, 132, 0, stream>>>(masks, mpk);
    cat_bias<<<(QKVN+255)/256, 256, 0, stream>>>(bq, bk, bv, bqkv);

    // 2. LN1
    ln_kernel<<<NS, 256, 0, stream>>>(x, g1, be1, xn_b, xn_f);

    // 3. fused QKV GEMM (2-phase kernel, handles M edge)
    gemm_nt<256,1,0,0><<<dim3(17,9,1),512,0,stream>>>(xn_b, WqkvT, bqkv, nullptr, nullptr, qkv,
        NS, QKVN, D_, D_, D_, QKVN, 1.f, 1, 0,0,0,0,0,0);

    // 4. v transpose (from qkv col 1536)
    transpose_v<<<dim3(D_/32, 33, B_), 256, 0, stream>>>(qkv, vT);

    // 5. scores = q @ k^T / 8
    gemm_nt<128,1,0,0><<<dim3(9,9,B_*H_),512,0,stream>>>(qkv, qkv + 768, nullptr, nullptr, nullptr, sc,
        S_, S_, 64, QKVN, QKVN, SP, 0.125f, H_,
        (long)S_*QKVN, 64, (long)S_*QKVN, 64, (long)H_*S_*SP, (long)S_*SP);

    // 6. fused rowmax + exp (in place)
    softexp<<<(B_*H_*S_+3)/4, 256, 0, stream>>>(sc, B_*H_*S_);

    // 7. PV -> h_all (main | masked contiguous)
    pv_kernel<false><<<dim3(17, B_*H_), 256, 0, stream>>>(sc, vT, nullptr, h_all);
    pv_kernel<true ><<<dim3(17 * B_ * M_ * H_), 256, 0, stream>>>(sc, vT, mpk, h_all + (size_t)NS*D_);

    // 8. merged Wp projection + residual (8-phase)
    gemm8p<0,3,0><<<dim3(73,3),512,0,stream>>>(h_all, WpT, bp, x, xn_f, x_all_pre,
        NALL, D_, D_, D_, D_, D_, 1.f);

    // 9. combined FFN over all rows (8-phase; POOL dead -> t_buf valid)
    ln_kernel<<<NALL, 256, 0, stream>>>(x_all_pre, g2, be2, xn_all, nullptr);
    gemm8p<1,0,1><<<dim3(73,12),512,0,stream>>>(xn_all, W1T, b1, nullptr, nullptr, t_buf,
        NALL, FF_, D_, D_, D_, FF_, 1.f);
    gemm8p<0,1,0><<<dim3(73,3),512,0,stream>>>(t_buf, W2T, b2, x_all_pre, nullptr, out,
        NALL, D_, FF_, FF_, FF_, D_, 1.f);

    // 10. img_idx as float values
    write_idx<<<1, 16, 0, stream>>>(out + (size_t)NS*D_ + (size_t)NMS*D_);
}

// Round 12
// 553.510 us; speedup vs baseline: 1.1694x; 1.1694x over previous
//
#include <hip/hip_runtime.h>
#include <hip/hip_bf16.h>

typedef unsigned short bf16;  // raw bf16 bit pattern
typedef short s16x8 __attribute__((ext_vector_type(8)));
typedef float f32x4 __attribute__((ext_vector_type(4)));

#define D_  768
#define FF_ 3072
#define H_  12
#define B_  2
#define S_  1025
#define M_  8
#define SP  1056      // padded score row length (16B-aligned rows)
#define NS  2050      // B_*S_
#define NMS 16400     // B_*M_*S_
#define NALL 18450    // NS + NMS
#define QKVN 2304     // 3*D_

__device__ __forceinline__ float b2f(bf16 u){ return __uint_as_float(((unsigned int)u) << 16); }
__device__ __forceinline__ bf16 f2b(float f){
    unsigned int b = __float_as_uint(f);
    unsigned int lsb = (b >> 16) & 1u;
    b += 0x7fffu + lsb;            // round-to-nearest-even
    return (bf16)(b >> 16);
}

// async global->LDS, 16B per lane. LDS dest = wave-uniform base + lane*16.
typedef __attribute__((address_space(1))) const void gvoid;
typedef __attribute__((address_space(3))) void lvoid;
__device__ __forceinline__ void gload16(const void* g, void* l){
    __builtin_amdgcn_global_load_lds((gvoid*)(unsigned long long)g,
        (lvoid*)(unsigned int)(unsigned long long)l, 16, 0, 0);
}

// bijective XCD swizzle (m204): contiguous work chunks per XCD
__device__ __forceinline__ int xcd_swz(int flat, int nwg){
    int q = nwg >> 3, r = nwg & 7;
    int xcd = flat & 7, slot = flat >> 3;
    int base = (xcd < r) ? xcd * (q + 1) : r * (q + 1) + (xcd - r) * q;
    return base + slot;
}

// ---------------- LayerNorm: f32 in -> bf16 out (+ optional f32 out) ----------------
__global__ __launch_bounds__(256) void ln_kernel(const float* __restrict__ in,
        const float* __restrict__ g, const float* __restrict__ be,
        bf16* __restrict__ out_bf, float* __restrict__ out_f32)
{
    int row = blockIdx.x;
    const float* r = in + (size_t)row * D_;
    int t = threadIdx.x;
    float v0 = r[t], v1 = r[t + 256], v2 = r[t + 512];
    float s  = v0 + v1 + v2;
    float ss = v0*v0 + v1*v1 + v2*v2;
    for (int o = 32; o; o >>= 1){ s += __shfl_xor(s, o); ss += __shfl_xor(ss, o); }
    __shared__ float sA[4], sB[4];
    int wid = t >> 6, lane = t & 63;
    if (lane == 0){ sA[wid] = s; sB[wid] = ss; }
    __syncthreads();
    s  = sA[0] + sA[1] + sA[2] + sA[3];
    ss = sB[0] + sB[1] + sB[2] + sB[3];
    float mean = s * (1.f / D_);
    float var  = ss * (1.f / D_) - mean * mean;
    float rstd = rsqrtf(var + 1e-6f);
    float vs[3] = {v0, v1, v2};
    #pragma unroll
    for (int i = 0; i < 3; i++){
        int c = t + i * 256;
        float y = (vs[i] - mean) * rstd * g[c] + be[c];
        out_bf[(size_t)row * D_ + c] = f2b(y);
        if (out_f32) out_f32[(size_t)row * D_ + c] = y;
    }
}

// ---------------- weight transpose f32 [K][N] -> bf16 [N][K] ----------------
__global__ __launch_bounds__(256) void transpose_w(const float* __restrict__ W,
        bf16* __restrict__ WT, int K, int N)
{
    __shared__ float tile[32][33];
    int n0 = blockIdx.x * 32, k0 = blockIdx.y * 32;
    int tx = threadIdx.x & 31, ty = threadIdx.x >> 5;
    #pragma unroll
    for (int i = 0; i < 4; i++)
        tile[ty + i*8][tx] = W[(size_t)(k0 + ty + i*8) * N + n0 + tx];
    __syncthreads();
    #pragma unroll
    for (int i = 0; i < 4; i++)
        WT[(size_t)(n0 + ty + i*8) * K + k0 + tx] = f2b(tile[tx][ty + i*8]);
}

// ---------------- v (qkv col 1536+) [B,S,2304] -> vT [B,D,SP] bf16 ----------------
__global__ __launch_bounds__(256) void transpose_v(const bf16* __restrict__ qkv,
        bf16* __restrict__ vT)
{
    __shared__ bf16 tile[32][33];
    int c0 = blockIdx.x * 32, s0 = blockIdx.y * 32, b = blockIdx.z;
    int tx = threadIdx.x & 31, ty = threadIdx.x >> 5;
    #pragma unroll
    for (int i = 0; i < 4; i++){
        int s = s0 + ty + i*8;
        tile[ty + i*8][tx] = (s < S_) ? qkv[((size_t)b * S_ + s) * QKVN + 1536 + c0 + tx] : (bf16)0;
    }
    __syncthreads();
    #pragma unroll
    for (int i = 0; i < 4; i++){
        int c = c0 + ty + i*8, s = s0 + tx;
        vT[((size_t)b * D_ + c) * SP + s] = tile[tx][ty + i*8];
    }
}

// ---------------- fused row-max + E = exp(s - max) in place; pads -> 0 ----------------
__global__ __launch_bounds__(256) void softexp(bf16* __restrict__ sc, int nrows)
{
    int wid = threadIdx.x >> 6, lane = threadIdx.x & 63;
    int row = blockIdx.x * 4 + wid;
    if (row >= nrows) return;
    bf16* srow = sc + (size_t)row * SP;
    s16x8 v0 = *(s16x8*)(srow + lane * 8);
    s16x8 v1 = *(s16x8*)(srow + 512 + lane * 8);
    s16x8 v2 = {0,0,0,0,0,0,0,0};
    if (lane < 4) v2 = *(s16x8*)(srow + 1024 + lane * 8);
    float m = -1e30f;
    #pragma unroll
    for (int e = 0; e < 8; e++) m = fmaxf(m, b2f((bf16)v0[e]));
    #pragma unroll
    for (int e = 0; e < 8; e++) m = fmaxf(m, b2f((bf16)v1[e]));
    if (lane == 0) m = fmaxf(m, b2f((bf16)v2[0]));
    for (int o = 32; o; o >>= 1) m = fmaxf(m, __shfl_xor(m, o));
    s16x8 o0, o1, o2;
    #pragma unroll
    for (int e = 0; e < 8; e++) o0[e] = (short)f2b(__expf(b2f((bf16)v0[e]) - m));
    #pragma unroll
    for (int e = 0; e < 8; e++) o1[e] = (short)f2b(__expf(b2f((bf16)v1[e]) - m));
    #pragma unroll
    for (int e = 0; e < 8; e++){
        int col = 1024 + lane * 8 + e;
        o2[e] = (col < S_) ? (short)f2b(__expf(b2f((bf16)v2[e]) - m)) : (short)0;
    }
    *(s16x8*)(srow + lane * 8) = o0;
    *(s16x8*)(srow + 512 + lane * 8) = o1;
    if (lane < 4) *(s16x8*)(srow + 1024 + lane * 8) = o2;
}

// ---------------- pack masks into per-(b,m) col bitmask (132 bytes) ----------------
__global__ void pack_masks(const int* __restrict__ masks, unsigned char* __restrict__ mpk)
{
    int g = blockIdx.x;          // 0..15
    int i = threadIdx.x;         // 0..131
    unsigned char v = 0;
    for (int j = 0; j < 8; j++){
        int col = i * 8 + j;
        if (col >= 1 && col <= 1024 && masks[(size_t)g * 1024 + col - 1] != 0) v |= (1 << j);
    }
    mpk[g * 132 + i] = v;
}

// ---------------- concat qkv bias ----------------
__global__ void cat_bias(const float* __restrict__ a, const float* __restrict__ b,
        const float* __restrict__ c, float* __restrict__ o)
{
    int i = blockIdx.x * 256 + threadIdx.x;
    if (i >= QKVN) return;
    o[i] = (i < 768) ? a[i] : (i < 1536 ? b[i - 768] : c[i - 1536]);
}

// ---------------- PV: (E [⊙mask]) @ V, dbuf staging, denom in-kernel ----------------
template<bool MASKED>
__global__ __launch_bounds__(256) void pv_kernel(const bf16* __restrict__ E,
        const bf16* __restrict__ vT, const unsigned char* __restrict__ mpk,
        bf16* __restrict__ out)
{
    __shared__ __align__(16) bf16 Ps[2][2048];
    __shared__ __align__(16) bf16 Vs[2][2048];
    __shared__ unsigned char mbytes[136];
    __shared__ float dinv[64];
    int h, g, b, q0;
    if (MASKED){
        int work = xcd_swz(blockIdx.x, 17 * B_ * M_ * H_);
        int m = work & 7; int rest = work >> 3;
        int q0b = rest % 17; int zbh = rest / 17;
        b = zbh / H_; h = zbh % H_;
        g = b * M_ + m;
        q0 = q0b * 64;
    } else {
        int z = blockIdx.y; h = z % H_; g = z / H_; b = g;
        q0 = blockIdx.x * 64;
    }
    bool fullq = (q0 + 64 <= S_);
    int t = threadIdx.x, w = t >> 6, l = t & 63;
    if (MASKED && t < 132) mbytes[t] = mpk[g * 132 + t];
    int row_l = t >> 2;
    int gch = (t & 3) ^ ((t >> 3) & 3);        // swizzled stage chunk
    const bf16* gP = E + ((size_t)(b * H_ + h) * S_ + q0 + row_l) * SP + gch * 8;
    const bf16* gV = vT + ((size_t)b * D_ + h * 64 + row_l) * SP + gch * 8;
    int lr = l & 15;
    int lc = l >> 4;                           // logical chunk
    int ca = lc ^ ((lr >> 1) & 3);             // swizzled read slot
    f32x4 acc[4];
    #pragma unroll
    for (int n = 0; n < 4; n++){ acc[n][0]=0.f; acc[n][1]=0.f; acc[n][2]=0.f; acc[n][3]=0.f; }
    float dsum = 0.f;
    bf16 *Pc = Ps[0], *Pa = Ps[1], *Vc = Vs[0], *Va = Vs[1];
    auto stage = [&](int k0, bf16* Pd, bf16* Vd){
        gload16(gV + k0, Vd + w * 512);
        if (fullq) gload16(gP + k0, Pd + w * 512);
        else {
            s16x8 p = {0,0,0,0,0,0,0,0};
            if (q0 + row_l < S_) p = *(const s16x8*)(gP + k0);
            *(s16x8*)&Pd[row_l * 32 + (t & 3) * 8] = p;
        }
    };
    stage(0, Pc, Vc);
    __syncthreads();
    for (int it = 0; it < 33; ++it){
        if (it < 32) stage(it * 32 + 32, Pa, Va);
        s16x8 a = *(s16x8*)&Pc[(w * 16 + lr) * 32 + ca * 8];
        if (MASKED){
            int mb = mbytes[it * 4 + lc];
            #pragma unroll
            for (int j = 0; j < 8; j++) if (!((mb >> j) & 1)) a[j] = 0;
        }
        #pragma unroll
        for (int j = 0; j < 8; j++) dsum += b2f((bf16)a[j]);
        #pragma unroll
        for (int n = 0; n < 4; n++){
            s16x8 bb = *(s16x8*)&Vc[(n * 16 + lr) * 32 + ca * 8];
            acc[n] = __builtin_amdgcn_mfma_f32_16x16x32_bf16(a, bb, acc[n], 0, 0, 0);
        }
        __syncthreads();
        bf16* tp;
        tp = Pc; Pc = Pa; Pa = tp;
        tp = Vc; Vc = Va; Va = tp;
    }
    dsum += __shfl_xor(dsum, 16);
    dsum += __shfl_xor(dsum, 32);
    if (l < 16) dinv[w * 16 + l] = 1.f / dsum;
    __syncthreads();
    int qb = q0 + w * 16 + (l >> 4) * 4;
    #pragma unroll
    for (int n = 0; n < 4; n++)
        #pragma unroll
        for (int e = 0; e < 4; e++){
            int qq = qb + e;
            if (qq < S_){
                float inv = dinv[w * 16 + (l >> 4) * 4 + e];
                out[((size_t)g * S_ + qq) * D_ + h * 64 + n * 16 + lr] = f2b(acc[n][e] * inv);
            }
        }
}

// ---------------- generic NT bf16 MFMA GEMM ----------------
// 128x128 tile, 8 waves (512 thr), wave tile 64x32 (2M x 4N wave grid).
// 4-buffer, lookahead-2, counted vmcnt, SINGLE barrier per K-step:
// stage(it+2) writes buf (it+2)&3, disjoint from readers of it&3 and laggards
// of (it-1)&3 -> trailing barrier provably unnecessary.
#define GBM 128
#define GBN 128
#define GBK 32

template<int OUTBF, int RESM, int DOGELU>
__global__ __launch_bounds__(512, 4) void gemm_nt(
        const bf16* __restrict__ A, const bf16* __restrict__ Bt,
        const float* __restrict__ bias, const float* __restrict__ res,
        const float* __restrict__ res2,
        void* __restrict__ Cp,
        int Mm, int Nn, int Kk, int lda, int ldb, int ldc,
        float scale, int ZH,
        long a_z1, long a_z2, long b_z1, long b_z2, long c_z1, long c_z2)
{
    __shared__ __align__(16) bf16 As[4][GBM * GBK];   // 4 x 8 KB
    __shared__ __align__(16) bf16 Bs[4][GBN * GBK];   // 64 KB total
    int z = blockIdx.z;
    int z1 = z / ZH, z2 = z % ZH;
    const bf16* Ab = A + z1 * a_z1 + z2 * a_z2;
    const bf16* Bb = Bt + z1 * b_z1 + z2 * b_z2;
    size_t c_off = (size_t)(z1 * c_z1 + z2 * c_z2);
    int gx = gridDim.x, gy = gridDim.y;
    int flat = blockIdx.y * gx + blockIdx.x;
    int work = xcd_swz(flat, gx * gy);
    int m0 = (work / gy) * GBM, n0 = (work % gy) * GBN;
    int t = threadIdx.x, w = t >> 6, l = t & 63;
    int wm = (w >> 2) * 64, wn = (w & 3) * 32;   // 2M x 4N wave grid
    int lr = l & 15;
    int ca = (l >> 4) ^ ((lr >> 1) & 3);       // swizzled read slot
    int srow = t >> 2;                         // 0..127 (512 threads)
    int gch = (t & 3) ^ ((t >> 3) & 3);        // swizzled stage chunk
    bool full = (m0 + GBM <= Mm) && (n0 + GBN <= Nn);
    const bf16* gA = Ab + (size_t)(m0 + srow) * lda + gch * 8;
    const bf16* gB = Bb + (size_t)(n0 + srow) * ldb + gch * 8;
    f32x4 acc[4][2];
    #pragma unroll
    for (int i = 0; i < 4; i++)
        #pragma unroll
        for (int j = 0; j < 2; j++){ acc[i][j][0]=0.f; acc[i][j][1]=0.f; acc[i][j][2]=0.f; acc[i][j][3]=0.f; }

    int nt = Kk >> 5;
    auto compute = [&](const bf16* Ac, const bf16* Bc){
        s16x8 af[4], bfr[2];
        #pragma unroll
        for (int i = 0; i < 4; i++) af[i] = *(const s16x8*)&Ac[(wm + i * 16 + lr) * 32 + ca * 8];
        #pragma unroll
        for (int j = 0; j < 2; j++) bfr[j] = *(const s16x8*)&Bc[(wn + j * 16 + lr) * 32 + ca * 8];
        #pragma unroll
        for (int i = 0; i < 4; i++)
            #pragma unroll
            for (int j = 0; j < 2; j++)
                acc[i][j] = __builtin_amdgcn_mfma_f32_16x16x32_bf16(af[i], bfr[j], acc[i][j], 0, 0, 0);
    };

    if (full){
        auto stage = [&](int k0, bf16* Ad, bf16* Bd){
            gload16(gA + k0, Ad + w * 512);    // wave w covers rows 16w..16w+15
            gload16(gB + k0, Bd + w * 512);
        };
        stage(0, As[0], Bs[0]);
        if (nt > 1) stage(32, As[1], Bs[1]);
        for (int it = 0; it < nt; ++it){
            if (it + 2 < nt){
                stage((it + 2) << 5, As[(it + 2) & 3], Bs[(it + 2) & 3]);
                asm volatile("s_waitcnt vmcnt(4)" ::: "memory");
            } else if (it + 1 < nt){
                asm volatile("s_waitcnt vmcnt(2)" ::: "memory");
            } else {
                asm volatile("s_waitcnt vmcnt(0)" ::: "memory");
            }
            __builtin_amdgcn_sched_barrier(0);
            __builtin_amdgcn_s_barrier();      // all waves' stage(it) landed
            __builtin_amdgcn_sched_barrier(0);
            compute(As[it & 3], Bs[it & 3]);   // no trailing barrier (4-buf proof)
        }
    } else {
        auto stage_e = [&](int k0, bf16* Ad, bf16* Bd){
            s16x8 z8 = {0,0,0,0,0,0,0,0};
            s16x8 va = z8; if (m0 + srow < Mm) va = *(const s16x8*)(gA + k0);
            *(s16x8*)&Ad[srow * 32 + (t & 3) * 8] = va;
            s16x8 vb = z8; if (n0 + srow < Nn) vb = *(const s16x8*)(gB + k0);
            *(s16x8*)&Bd[srow * 32 + (t & 3) * 8] = vb;
        };
        bf16 *Ac = As[0], *Aa = As[1], *Bc = Bs[0], *Ba = Bs[1];
        stage_e(0, Ac, Bc);
        __syncthreads();
        for (int it = 0; it < nt; ++it){
            if (it + 1 < nt) stage_e((it + 1) << 5, Aa, Ba);
            compute(Ac, Bc);
            __syncthreads();
            bf16* tp;
            tp = Ac; Ac = Aa; Aa = tp;
            tp = Bc; Bc = Ba; Ba = tp;
        }
    }

    #pragma unroll
    for (int i = 0; i < 4; i++)
        #pragma unroll
        for (int j = 0; j < 2; j++)
            #pragma unroll
            for (int e = 0; e < 4; e++){
                int rr = m0 + wm + i * 16 + (l >> 4) * 4 + e;
                int cc = n0 + wn + j * 16 + lr;
                if (rr < Mm && cc < Nn){
                    float v = acc[i][j][e] * scale;
                    if (bias) v += bias[cc];
                    if (DOGELU) v = 0.5f * v * (1.f + erff(v * 0.70710678118654752f));
                    if (RESM == 1) v += res[(size_t)rr * 768 + cc];
                    else if (RESM == 3){
                        if (rr < NS) v += res[(size_t)rr * 768 + cc];
                        else {
                            int mr = rr - NS;
                            int rb = mr / 8200, rs = mr % 1025;
                            v += res2[((size_t)rb * 1025 + rs) * 768 + cc];
                        }
                    }
                    if (OUTBF) ((bf16*)Cp)[c_off + (size_t)rr * ldc + cc] = f2b(v);
                    else       ((float*)Cp)[c_off + (size_t)rr * ldc + cc] = v;
                }
            }
}

__global__ void write_idx(float* o){ o[threadIdx.x] = (float)(threadIdx.x >> 3); }

// =============================== host ===============================
extern "C" void kernel_launch(void* const* d_in, const int* in_sizes, int n_in,
                              void* d_out, int out_size, void* d_ws, size_t ws_size,
                              hipStream_t stream)
{
    const float* x    = (const float*)d_in[0];
    const int*   masks= (const int*)d_in[1];
    const float* Wq = (const float*)d_in[2];
    const float* bq = (const float*)d_in[3];
    const float* Wk = (const float*)d_in[4];
    const float* bk = (const float*)d_in[5];
    const float* Wv = (const float*)d_in[6];
    const float* bv = (const float*)d_in[7];
    const float* Wp = (const float*)d_in[8];
    const float* bp = (const float*)d_in[9];
    const float* W1 = (const float*)d_in[10];
    const float* b1 = (const float*)d_in[11];
    const float* W2 = (const float*)d_in[12];
    const float* b2 = (const float*)d_in[13];
    const float* g1  = (const float*)d_in[14];
    const float* be1 = (const float*)d_in[15];
    const float* g2  = (const float*)d_in[16];
    const float* be2 = (const float*)d_in[17];
    float* out = (float*)d_out;

    char* ws = (char*)d_ws;
    size_t off = 0;
    auto alloc = [&](size_t bytes)->char* {
        char* p = ws + off;
        off = (off + bytes + 255) & ~(size_t)255;
        return p;
    };
    // persistent through FFN
    bf16*  W1T   = (bf16*) alloc((size_t)FF_ * D_ * 2);
    bf16*  W2T   = (bf16*) alloc((size_t)D_ * FF_ * 2);
    float* x_all_pre = (float*)alloc((size_t)NALL * D_ * 4);   // main 0..2049 | masked 2050..
    bf16*  xn_all    = (bf16*) alloc((size_t)NALL * D_ * 2);
    // POOL: everything dead by FFN time; t_buf overlays it
    size_t pool_need = (size_t)NALL * FF_ * 2;                 // 113.4 MB for t_buf
    char* pool = alloc(pool_need);
    size_t poff = 0;
    auto palloc = [&](size_t bytes)->char* {
        char* p = pool + poff;
        poff = (poff + bytes + 255) & ~(size_t)255;
        return p;
    };
    float* xn_f  = (float*)palloc((size_t)NS * D_ * 4);
    bf16*  xn_b  = (bf16*) palloc((size_t)NS * D_ * 2);
    bf16*  WqkvT = (bf16*) palloc((size_t)QKVN * D_ * 2);
    float* bqkv  = (float*)palloc((size_t)QKVN * 4);
    bf16*  WpT   = (bf16*) palloc((size_t)D_ * D_ * 2);
    bf16*  qkv   = (bf16*) palloc((size_t)NS * QKVN * 2);
    bf16*  sc    = (bf16*) palloc((size_t)B_ * H_ * S_ * SP * 2);   // scores -> E
    bf16*  vT    = (bf16*) palloc((size_t)B_ * D_ * SP * 2);
    unsigned char* mpk = (unsigned char*)palloc(16 * 132);
    bf16*  h_all = (bf16*) palloc((size_t)NALL * D_ * 2);           // main | masked PV out
    bf16*  t_buf = (bf16*)pool;    // valid only after all POOL members are dead

    // 1. weight transposes + mask pack + bias concat
    transpose_w<<<dim3(D_/32, D_/32), 256, 0, stream>>>(Wq, WqkvT, D_, D_);
    transpose_w<<<dim3(D_/32, D_/32), 256, 0, stream>>>(Wk, WqkvT + (size_t)768*768, D_, D_);
    transpose_w<<<dim3(D_/32, D_/32), 256, 0, stream>>>(Wv, WqkvT + (size_t)1536*768, D_, D_);
    transpose_w<<<dim3(D_/32, D_/32), 256, 0, stream>>>(Wp, WpT, D_, D_);
    transpose_w<<<dim3(FF_/32, D_/32), 256, 0, stream>>>(W1, W1T, D_, FF_);
    transpose_w<<<dim3(D_/32, FF_/32), 256, 0, stream>>>(W2, W2T, FF_, D_);
    pack_masks<<<16, 132, 0, stream>>>(masks, mpk);
    cat_bias<<<(QKVN+255)/256, 256, 0, stream>>>(bq, bk, bv, bqkv);

    // 2. LN1
    ln_kernel<<<NS, 256, 0, stream>>>(x, g1, be1, xn_b, xn_f);

    // 3. fused QKV GEMM: [2050,768] @ [2304,768]^T
    gemm_nt<1,0,0><<<dim3(17,18,1),512,0,stream>>>(xn_b, WqkvT, bqkv, nullptr, nullptr, qkv,
        NS, QKVN, D_, D_, D_, QKVN, 1.f, 1, 0,0,0,0,0,0);

    // 4. v transpose (from qkv col 1536)
    transpose_v<<<dim3(D_/32, 33, B_), 256, 0, stream>>>(qkv, vT);

    // 5. scores = q @ k^T / 8 (q at qkv col 0, k at col 768)
    gemm_nt<1,0,0><<<dim3(9,9,B_*H_),512,0,stream>>>(qkv, qkv + 768, nullptr, nullptr, nullptr, sc,
        S_, S_, 64, QKVN, QKVN, SP, 0.125f, H_,
        (long)S_*QKVN, 64, (long)S_*QKVN, 64, (long)H_*S_*SP, (long)S_*SP);

    // 6. fused rowmax + exp (in place)
    softexp<<<(B_*H_*S_+3)/4, 256, 0, stream>>>(sc, B_*H_*S_);

    // 7. PV (denominator computed in-kernel) -> h_all (main | masked contiguous)
    pv_kernel<false><<<dim3(17, B_*H_), 256, 0, stream>>>(sc, vT, nullptr, h_all);
    pv_kernel<true ><<<dim3(17 * B_ * M_ * H_), 256, 0, stream>>>(sc, vT, mpk, h_all + (size_t)NS*D_);

    // 8. merged Wp projection + residual (main: x, masked: broadcast xn_f)
    gemm_nt<0,3,0><<<dim3(145,6),512,0,stream>>>(h_all, WpT, bp, x, xn_f, x_all_pre,
        NALL, D_, D_, D_, D_, D_, 1.f, 1, 0,0,0,0,0,0);

    // 9. combined FFN over all 18450 rows (POOL dead now -> t_buf valid)
    ln_kernel<<<NALL, 256, 0, stream>>>(x_all_pre, g2, be2, xn_all, nullptr);
    gemm_nt<1,0,1><<<dim3(145,24),512,0,stream>>>(xn_all, W1T, b1, nullptr, nullptr, t_buf,
        NALL, FF_, D_, D_, D_, FF_, 1.f, 1, 0,0,0,0,0,0);
    gemm_nt<0,1,0><<<dim3(145,6),512,0,stream>>>(t_buf, W2T, b2, x_all_pre, nullptr, out,
        NALL, D_, FF_, FF_, FF_, D_, 1.f, 1, 0,0,0,0,0,0);

    // 10. img_idx as float values
    write_idx<<<1, 16, 0, stream>>>(out + (size_t)NS*D_ + (size_t)NMS*D_);
}

// Round 13
// 539.629 us; speedup vs baseline: 1.1994x; 1.0257x over previous
//
#include <hip/hip_runtime.h>
#include <hip/hip_bf16.h>

typedef unsigned short bf16;  // raw bf16 bit pattern
typedef short s16x8 __attribute__((ext_vector_type(8)));
typedef float f32x4 __attribute__((ext_vector_type(4)));

#define D_  768
#define FF_ 3072
#define H_  12
#define B_  2
#define S_  1025
#define M_  8
#define SP  1056      // padded score row length (16B-aligned rows)
#define NS  2050      // B_*S_
#define NMS 16400     // B_*M_*S_
#define NALL 18450    // NS + NMS
#define QKVN 2304     // 3*D_

__device__ __forceinline__ float b2f(bf16 u){ return __uint_as_float(((unsigned int)u) << 16); }
__device__ __forceinline__ bf16 f2b(float f){
    unsigned int b = __float_as_uint(f);
    unsigned int lsb = (b >> 16) & 1u;
    b += 0x7fffu + lsb;            // round-to-nearest-even
    return (bf16)(b >> 16);
}

// async global->LDS, 16B per lane. LDS dest = wave-uniform base + lane*16.
typedef __attribute__((address_space(1))) const void gvoid;
typedef __attribute__((address_space(3))) void lvoid;
__device__ __forceinline__ void gload16(const void* g, void* l){
    __builtin_amdgcn_global_load_lds((gvoid*)(unsigned long long)g,
        (lvoid*)(unsigned int)(unsigned long long)l, 16, 0, 0);
}

// bijective XCD swizzle (m204): contiguous work chunks per XCD
__device__ __forceinline__ int xcd_swz(int flat, int nwg){
    int q = nwg >> 3, r = nwg & 7;
    int xcd = flat & 7, slot = flat >> 3;
    int base = (xcd < r) ? xcd * (q + 1) : r * (q + 1) + (xcd - r) * q;
    return base + slot;
}

// ---------------- LayerNorm: f32 in -> bf16 out (+ optional f32 out) ----------------
__global__ __launch_bounds__(256) void ln_kernel(const float* __restrict__ in,
        const float* __restrict__ g, const float* __restrict__ be,
        bf16* __restrict__ out_bf, float* __restrict__ out_f32)
{
    int row = blockIdx.x;
    const float* r = in + (size_t)row * D_;
    int t = threadIdx.x;
    float v0 = r[t], v1 = r[t + 256], v2 = r[t + 512];
    float s  = v0 + v1 + v2;
    float ss = v0*v0 + v1*v1 + v2*v2;
    for (int o = 32; o; o >>= 1){ s += __shfl_xor(s, o); ss += __shfl_xor(ss, o); }
    __shared__ float sA[4], sB[4];
    int wid = t >> 6, lane = t & 63;
    if (lane == 0){ sA[wid] = s; sB[wid] = ss; }
    __syncthreads();
    s  = sA[0] + sA[1] + sA[2] + sA[3];
    ss = sB[0] + sB[1] + sB[2] + sB[3];
    float mean = s * (1.f / D_);
    float var  = ss * (1.f / D_) - mean * mean;
    float rstd = rsqrtf(var + 1e-6f);
    float vs[3] = {v0, v1, v2};
    #pragma unroll
    for (int i = 0; i < 3; i++){
        int c = t + i * 256;
        float y = (vs[i] - mean) * rstd * g[c] + be[c];
        out_bf[(size_t)row * D_ + c] = f2b(y);
        if (out_f32) out_f32[(size_t)row * D_ + c] = y;
    }
}

// ---------------- weight transpose f32 [K][N] -> bf16 [N][K] ----------------
__global__ __launch_bounds__(256) void transpose_w(const float* __restrict__ W,
        bf16* __restrict__ WT, int K, int N)
{
    __shared__ float tile[32][33];
    int n0 = blockIdx.x * 32, k0 = blockIdx.y * 32;
    int tx = threadIdx.x & 31, ty = threadIdx.x >> 5;
    #pragma unroll
    for (int i = 0; i < 4; i++)
        tile[ty + i*8][tx] = W[(size_t)(k0 + ty + i*8) * N + n0 + tx];
    __syncthreads();
    #pragma unroll
    for (int i = 0; i < 4; i++)
        WT[(size_t)(n0 + ty + i*8) * K + k0 + tx] = f2b(tile[tx][ty + i*8]);
}

// ---------------- v (qkv col 1536+) [B,S,2304] -> vT [B,D,SP] bf16 ----------------
__global__ __launch_bounds__(256) void transpose_v(const bf16* __restrict__ qkv,
        bf16* __restrict__ vT)
{
    __shared__ bf16 tile[32][33];
    int c0 = blockIdx.x * 32, s0 = blockIdx.y * 32, b = blockIdx.z;
    int tx = threadIdx.x & 31, ty = threadIdx.x >> 5;
    #pragma unroll
    for (int i = 0; i < 4; i++){
        int s = s0 + ty + i*8;
        tile[ty + i*8][tx] = (s < S_) ? qkv[((size_t)b * S_ + s) * QKVN + 1536 + c0 + tx] : (bf16)0;
    }
    __syncthreads();
    #pragma unroll
    for (int i = 0; i < 4; i++){
        int c = c0 + ty + i*8, s = s0 + tx;
        vT[((size_t)b * D_ + c) * SP + s] = tile[tx][ty + i*8];
    }
}

// ---------------- fused row-max + E = exp(s - max) in place; pads -> 0 ----------------
__global__ __launch_bounds__(256) void softexp(bf16* __restrict__ sc, int nrows)
{
    int wid = threadIdx.x >> 6, lane = threadIdx.x & 63;
    int row = blockIdx.x * 4 + wid;
    if (row >= nrows) return;
    bf16* srow = sc + (size_t)row * SP;
    s16x8 v0 = *(s16x8*)(srow + lane * 8);
    s16x8 v1 = *(s16x8*)(srow + 512 + lane * 8);
    s16x8 v2 = {0,0,0,0,0,0,0,0};
    if (lane < 4) v2 = *(s16x8*)(srow + 1024 + lane * 8);
    float m = -1e30f;
    #pragma unroll
    for (int e = 0; e < 8; e++) m = fmaxf(m, b2f((bf16)v0[e]));
    #pragma unroll
    for (int e = 0; e < 8; e++) m = fmaxf(m, b2f((bf16)v1[e]));
    if (lane == 0) m = fmaxf(m, b2f((bf16)v2[0]));
    for (int o = 32; o; o >>= 1) m = fmaxf(m, __shfl_xor(m, o));
    s16x8 o0, o1, o2;
    #pragma unroll
    for (int e = 0; e < 8; e++) o0[e] = (short)f2b(__expf(b2f((bf16)v0[e]) - m));
    #pragma unroll
    for (int e = 0; e < 8; e++) o1[e] = (short)f2b(__expf(b2f((bf16)v1[e]) - m));
    #pragma unroll
    for (int e = 0; e < 8; e++){
        int col = 1024 + lane * 8 + e;
        o2[e] = (col < S_) ? (short)f2b(__expf(b2f((bf16)v2[e]) - m)) : (short)0;
    }
    *(s16x8*)(srow + lane * 8) = o0;
    *(s16x8*)(srow + 512 + lane * 8) = o1;
    if (lane < 4) *(s16x8*)(srow + 1024 + lane * 8) = o2;
}

// ---------------- pack masks into per-(b,m) col bitmask (132 bytes) ----------------
__global__ void pack_masks(const int* __restrict__ masks, unsigned char* __restrict__ mpk)
{
    int g = blockIdx.x;          // 0..15
    int i = threadIdx.x;         // 0..131
    unsigned char v = 0;
    for (int j = 0; j < 8; j++){
        int col = i * 8 + j;
        if (col >= 1 && col <= 1024 && masks[(size_t)g * 1024 + col - 1] != 0) v |= (1 << j);
    }
    mpk[g * 132 + i] = v;
}

// ---------------- concat qkv bias ----------------
__global__ void cat_bias(const float* __restrict__ a, const float* __restrict__ b,
        const float* __restrict__ c, float* __restrict__ o)
{
    int i = blockIdx.x * 256 + threadIdx.x;
    if (i >= QKVN) return;
    o[i] = (i < 768) ? a[i] : (i < 1536 ? b[i - 768] : c[i - 1536]);
}

// ---------------- PV: (E [⊙mask]) @ V, dbuf staging, denom in-kernel ----------------
template<bool MASKED>
__global__ __launch_bounds__(256) void pv_kernel(const bf16* __restrict__ E,
        const bf16* __restrict__ vT, const unsigned char* __restrict__ mpk,
        bf16* __restrict__ out)
{
    __shared__ __align__(16) bf16 Ps[2][2048];
    __shared__ __align__(16) bf16 Vs[2][2048];
    __shared__ unsigned char mbytes[136];
    __shared__ float dinv[64];
    int h, g, b, q0;
    if (MASKED){
        int work = xcd_swz(blockIdx.x, 17 * B_ * M_ * H_);
        int m = work & 7; int rest = work >> 3;
        int q0b = rest % 17; int zbh = rest / 17;
        b = zbh / H_; h = zbh % H_;
        g = b * M_ + m;
        q0 = q0b * 64;
    } else {
        int z = blockIdx.y; h = z % H_; g = z / H_; b = g;
        q0 = blockIdx.x * 64;
    }
    bool fullq = (q0 + 64 <= S_);
    int t = threadIdx.x, w = t >> 6, l = t & 63;
    if (MASKED && t < 132) mbytes[t] = mpk[g * 132 + t];
    int row_l = t >> 2;
    int gch = (t & 3) ^ ((t >> 3) & 3);        // swizzled stage chunk
    const bf16* gP = E + ((size_t)(b * H_ + h) * S_ + q0 + row_l) * SP + gch * 8;
    const bf16* gV = vT + ((size_t)b * D_ + h * 64 + row_l) * SP + gch * 8;
    int lr = l & 15;
    int lc = l >> 4;                           // logical chunk
    int ca = lc ^ ((lr >> 1) & 3);             // swizzled read slot
    f32x4 acc[4];
    #pragma unroll
    for (int n = 0; n < 4; n++){ acc[n][0]=0.f; acc[n][1]=0.f; acc[n][2]=0.f; acc[n][3]=0.f; }
    float dsum = 0.f;
    bf16 *Pc = Ps[0], *Pa = Ps[1], *Vc = Vs[0], *Va = Vs[1];
    auto stage = [&](int k0, bf16* Pd, bf16* Vd){
        gload16(gV + k0, Vd + w * 512);
        if (fullq) gload16(gP + k0, Pd + w * 512);
        else {
            s16x8 p = {0,0,0,0,0,0,0,0};
            if (q0 + row_l < S_) p = *(const s16x8*)(gP + k0);
            *(s16x8*)&Pd[row_l * 32 + (t & 3) * 8] = p;
        }
    };
    stage(0, Pc, Vc);
    __syncthreads();
    for (int it = 0; it < 33; ++it){
        if (it < 32) stage(it * 32 + 32, Pa, Va);
        s16x8 a = *(s16x8*)&Pc[(w * 16 + lr) * 32 + ca * 8];
        if (MASKED){
            int mb = mbytes[it * 4 + lc];
            #pragma unroll
            for (int j = 0; j < 8; j++) if (!((mb >> j) & 1)) a[j] = 0;
        }
        #pragma unroll
        for (int j = 0; j < 8; j++) dsum += b2f((bf16)a[j]);
        #pragma unroll
        for (int n = 0; n < 4; n++){
            s16x8 bb = *(s16x8*)&Vc[(n * 16 + lr) * 32 + ca * 8];
            acc[n] = __builtin_amdgcn_mfma_f32_16x16x32_bf16(a, bb, acc[n], 0, 0, 0);
        }
        __syncthreads();
        bf16* tp;
        tp = Pc; Pc = Pa; Pa = tp;
        tp = Vc; Vc = Va; Va = tp;
    }
    dsum += __shfl_xor(dsum, 16);
    dsum += __shfl_xor(dsum, 32);
    if (l < 16) dinv[w * 16 + l] = 1.f / dsum;
    __syncthreads();
    int qb = q0 + w * 16 + (l >> 4) * 4;
    #pragma unroll
    for (int n = 0; n < 4; n++)
        #pragma unroll
        for (int e = 0; e < 4; e++){
            int qq = qb + e;
            if (qq < S_){
                float inv = dinv[w * 16 + (l >> 4) * 4 + e];
                out[((size_t)g * S_ + qq) * D_ + h * 64 + n * 16 + lr] = f2b(acc[n][e] * inv);
            }
        }
}

// ---------------- generic NT bf16 MFMA GEMM ----------------
// 128x128 tile, 8 waves (512 thr), wave tile 64x32 (2M x 4N wave grid).
// 3-buf, lookahead-2, counted vmcnt, 2 barriers/step (round-8 proven base),
// steady loop unrolled x3 with STATIC buffer rotation (kills %3 addressing VALU).
#define GBM 128
#define GBN 128
#define GBK 32

template<int OUTBF, int RESM, int DOGELU>
__global__ __launch_bounds__(512) void gemm_nt(
        const bf16* __restrict__ A, const bf16* __restrict__ Bt,
        const float* __restrict__ bias, const float* __restrict__ res,
        const float* __restrict__ res2,
        void* __restrict__ Cp,
        int Mm, int Nn, int Kk, int lda, int ldb, int ldc,
        float scale, int ZH,
        long a_z1, long a_z2, long b_z1, long b_z2, long c_z1, long c_z2)
{
    __shared__ __align__(16) bf16 As[3][GBM * GBK];   // 3 x 8 KB
    __shared__ __align__(16) bf16 Bs[3][GBN * GBK];   // 48 KB total
    int z = blockIdx.z;
    int z1 = z / ZH, z2 = z % ZH;
    const bf16* Ab = A + z1 * a_z1 + z2 * a_z2;
    const bf16* Bb = Bt + z1 * b_z1 + z2 * b_z2;
    size_t c_off = (size_t)(z1 * c_z1 + z2 * c_z2);
    int gx = gridDim.x, gy = gridDim.y;
    int flat = blockIdx.y * gx + blockIdx.x;
    int work = xcd_swz(flat, gx * gy);
    int m0 = (work / gy) * GBM, n0 = (work % gy) * GBN;
    int t = threadIdx.x, w = t >> 6, l = t & 63;
    int wm = (w >> 2) * 64, wn = (w & 3) * 32;   // 2M x 4N wave grid
    int lr = l & 15;
    int ca = (l >> 4) ^ ((lr >> 1) & 3);       // swizzled read slot
    int srow = t >> 2;                         // 0..127 (512 threads)
    int gch = (t & 3) ^ ((t >> 3) & 3);        // swizzled stage chunk
    bool full = (m0 + GBM <= Mm) && (n0 + GBN <= Nn);
    const bf16* gA = Ab + (size_t)(m0 + srow) * lda + gch * 8;
    const bf16* gB = Bb + (size_t)(n0 + srow) * ldb + gch * 8;
    f32x4 acc[4][2];
    #pragma unroll
    for (int i = 0; i < 4; i++)
        #pragma unroll
        for (int j = 0; j < 2; j++){ acc[i][j][0]=0.f; acc[i][j][1]=0.f; acc[i][j][2]=0.f; acc[i][j][3]=0.f; }

    int nt = Kk >> 5;
    auto compute = [&](const bf16* Ac, const bf16* Bc){
        s16x8 af[4], bfr[2];
        #pragma unroll
        for (int i = 0; i < 4; i++) af[i] = *(const s16x8*)&Ac[(wm + i * 16 + lr) * 32 + ca * 8];
        #pragma unroll
        for (int j = 0; j < 2; j++) bfr[j] = *(const s16x8*)&Bc[(wn + j * 16 + lr) * 32 + ca * 8];
        #pragma unroll
        for (int i = 0; i < 4; i++)
            #pragma unroll
            for (int j = 0; j < 2; j++)
                acc[i][j] = __builtin_amdgcn_mfma_f32_16x16x32_bf16(af[i], bfr[j], acc[i][j], 0, 0, 0);
    };

    if (full){
        auto stage = [&](int k0, bf16* Ad, bf16* Bd){
            gload16(gA + k0, Ad + w * 512);    // wave w covers rows 16w..16w+15
            gload16(gB + k0, Bd + w * 512);
        };
        stage(0, As[0], Bs[0]);
        if (nt > 1) stage(32, As[1], Bs[1]);
        __syncthreads();                       // prologue drain

#define SUBSTEP(SI, CI, KST) \
        stage((KST), As[SI], Bs[SI]); \
        asm volatile("s_waitcnt vmcnt(4)" ::: "memory"); \
        __builtin_amdgcn_sched_barrier(0); \
        __builtin_amdgcn_s_barrier(); \
        __builtin_amdgcn_sched_barrier(0); \
        compute(As[CI], Bs[CI]); \
        __builtin_amdgcn_sched_barrier(0); \
        __builtin_amdgcn_s_barrier();

        int it = 0;
        for (; it + 5 < nt; it += 3){
            int kst = (it + 2) << 5;
            SUBSTEP(2, 0, kst)
            SUBSTEP(0, 1, kst + 32)
            SUBSTEP(1, 2, kst + 64)
        }
#undef SUBSTEP
        for (; it < nt; ++it){
            int ib = it % 3;
            if (it + 2 < nt){
                stage((it + 2) << 5, As[(it + 2) % 3], Bs[(it + 2) % 3]);
                asm volatile("s_waitcnt vmcnt(4)" ::: "memory");
            } else if (it + 1 < nt){
                asm volatile("s_waitcnt vmcnt(2)" ::: "memory");
            } else {
                asm volatile("s_waitcnt vmcnt(0)" ::: "memory");
            }
            __builtin_amdgcn_sched_barrier(0);
            __builtin_amdgcn_s_barrier();      // all waves' stage(it) landed
            __builtin_amdgcn_sched_barrier(0);
            compute(As[ib], Bs[ib]);
            __builtin_amdgcn_sched_barrier(0);
            __builtin_amdgcn_s_barrier();      // protect buf ib before reuse
        }
    } else {
        auto stage_e = [&](int k0, bf16* Ad, bf16* Bd){
            s16x8 z8 = {0,0,0,0,0,0,0,0};
            s16x8 va = z8; if (m0 + srow < Mm) va = *(const s16x8*)(gA + k0);
            *(s16x8*)&Ad[srow * 32 + (t & 3) * 8] = va;
            s16x8 vb = z8; if (n0 + srow < Nn) vb = *(const s16x8*)(gB + k0);
            *(s16x8*)&Bd[srow * 32 + (t & 3) * 8] = vb;
        };
        bf16 *Ac = As[0], *Aa = As[1], *Bc = Bs[0], *Ba = Bs[1];
        stage_e(0, Ac, Bc);
        __syncthreads();
        for (int it = 0; it < nt; ++it){
            if (it + 1 < nt) stage_e((it + 1) << 5, Aa, Ba);
            compute(Ac, Bc);
            __syncthreads();
            bf16* tp;
            tp = Ac; Ac = Aa; Aa = tp;
            tp = Bc; Bc = Ba; Ba = tp;
        }
    }

    #pragma unroll
    for (int i = 0; i < 4; i++)
        #pragma unroll
        for (int j = 0; j < 2; j++)
            #pragma unroll
            for (int e = 0; e < 4; e++){
                int rr = m0 + wm + i * 16 + (l >> 4) * 4 + e;
                int cc = n0 + wn + j * 16 + lr;
                if (rr < Mm && cc < Nn){
                    float v = acc[i][j][e] * scale;
                    if (bias) v += bias[cc];
                    if (DOGELU) v = 0.5f * v * (1.f + erff(v * 0.70710678118654752f));
                    if (RESM == 1) v += res[(size_t)rr * 768 + cc];
                    else if (RESM == 3){
                        if (rr < NS) v += res[(size_t)rr * 768 + cc];
                        else {
                            int mr = rr - NS;
                            int rb = mr / 8200, rs = mr % 1025;
                            v += res2[((size_t)rb * 1025 + rs) * 768 + cc];
                        }
                    }
                    if (OUTBF) ((bf16*)Cp)[c_off + (size_t)rr * ldc + cc] = f2b(v);
                    else       ((float*)Cp)[c_off + (size_t)rr * ldc + cc] = v;
                }
            }
}

__global__ void write_idx(float* o){ o[threadIdx.x] = (float)(threadIdx.x >> 3); }

// =============================== host ===============================
extern "C" void kernel_launch(void* const* d_in, const int* in_sizes, int n_in,
                              void* d_out, int out_size, void* d_ws, size_t ws_size,
                              hipStream_t stream)
{
    const float* x    = (const float*)d_in[0];
    const int*   masks= (const int*)d_in[1];
    const float* Wq = (const float*)d_in[2];
    const float* bq = (const float*)d_in[3];
    const float* Wk = (const float*)d_in[4];
    const float* bk = (const float*)d_in[5];
    const float* Wv = (const float*)d_in[6];
    const float* bv = (const float*)d_in[7];
    const float* Wp = (const float*)d_in[8];
    const float* bp = (const float*)d_in[9];
    const float* W1 = (const float*)d_in[10];
    const float* b1 = (const float*)d_in[11];
    const float* W2 = (const float*)d_in[12];
    const float* b2 = (const float*)d_in[13];
    const float* g1  = (const float*)d_in[14];
    const float* be1 = (const float*)d_in[15];
    const float* g2  = (const float*)d_in[16];
    const float* be2 = (const float*)d_in[17];
    float* out = (float*)d_out;

    char* ws = (char*)d_ws;
    size_t off = 0;
    auto alloc = [&](size_t bytes)->char* {
        char* p = ws + off;
        off = (off + bytes + 255) & ~(size_t)255;
        return p;
    };
    // persistent through FFN
    bf16*  W1T   = (bf16*) alloc((size_t)FF_ * D_ * 2);
    bf16*  W2T   = (bf16*) alloc((size_t)D_ * FF_ * 2);
    float* x_all_pre = (float*)alloc((size_t)NALL * D_ * 4);   // main 0..2049 | masked 2050..
    bf16*  xn_all    = (bf16*) alloc((size_t)NALL * D_ * 2);
    // POOL: everything dead by FFN time; t_buf overlays it
    size_t pool_need = (size_t)NALL * FF_ * 2;                 // 113.4 MB for t_buf
    char* pool = alloc(pool_need);
    size_t poff = 0;
    auto palloc = [&](size_t bytes)->char* {
        char* p = pool + poff;
        poff = (poff + bytes + 255) & ~(size_t)255;
        return p;
    };
    float* xn_f  = (float*)palloc((size_t)NS * D_ * 4);
    bf16*  xn_b  = (bf16*) palloc((size_t)NS * D_ * 2);
    bf16*  WqkvT = (bf16*) palloc((size_t)QKVN * D_ * 2);
    float* bqkv  = (float*)palloc((size_t)QKVN * 4);
    bf16*  WpT   = (bf16*) palloc((size_t)D_ * D_ * 2);
    bf16*  qkv   = (bf16*) palloc((size_t)NS * QKVN * 2);
    bf16*  sc    = (bf16*) palloc((size_t)B_ * H_ * S_ * SP * 2);   // scores -> E
    bf16*  vT    = (bf16*) palloc((size_t)B_ * D_ * SP * 2);
    unsigned char* mpk = (unsigned char*)palloc(16 * 132);
    bf16*  h_all = (bf16*) palloc((size_t)NALL * D_ * 2);           // main | masked PV out
    bf16*  t_buf = (bf16*)pool;    // valid only after all POOL members are dead

    // 1. weight transposes + mask pack + bias concat
    transpose_w<<<dim3(D_/32, D_/32), 256, 0, stream>>>(Wq, WqkvT, D_, D_);
    transpose_w<<<dim3(D_/32, D_/32), 256, 0, stream>>>(Wk, WqkvT + (size_t)768*768, D_, D_);
    transpose_w<<<dim3(D_/32, D_/32), 256, 0, stream>>>(Wv, WqkvT + (size_t)1536*768, D_, D_);
    transpose_w<<<dim3(D_/32, D_/32), 256, 0, stream>>>(Wp, WpT, D_, D_);
    transpose_w<<<dim3(FF_/32, D_/32), 256, 0, stream>>>(W1, W1T, D_, FF_);
    transpose_w<<<dim3(D_/32, FF_/32), 256, 0, stream>>>(W2, W2T, FF_, D_);
    pack_masks<<<16, 132, 0, stream>>>(masks, mpk);
    cat_bias<<<(QKVN+255)/256, 256, 0, stream>>>(bq, bk, bv, bqkv);

    // 2. LN1
    ln_kernel<<<NS, 256, 0, stream>>>(x, g1, be1, xn_b, xn_f);

    // 3. fused QKV GEMM: [2050,768] @ [2304,768]^T
    gemm_nt<1,0,0><<<dim3(17,18,1),512,0,stream>>>(xn_b, WqkvT, bqkv, nullptr, nullptr, qkv,
        NS, QKVN, D_, D_, D_, QKVN, 1.f, 1, 0,0,0,0,0,0);

    // 4. v transpose (from qkv col 1536)
    transpose_v<<<dim3(D_/32, 33, B_), 256, 0, stream>>>(qkv, vT);

    // 5. scores = q @ k^T / 8 (q at qkv col 0, k at col 768)
    gemm_nt<1,0,0><<<dim3(9,9,B_*H_),512,0,stream>>>(qkv, qkv + 768, nullptr, nullptr, nullptr, sc,
        S_, S_, 64, QKVN, QKVN, SP, 0.125f, H_,
        (long)S_*QKVN, 64, (long)S_*QKVN, 64, (long)H_*S_*SP, (long)S_*SP);

    // 6. fused rowmax + exp (in place)
    softexp<<<(B_*H_*S_+3)/4, 256, 0, stream>>>(sc, B_*H_*S_);

    // 7. PV (denominator computed in-kernel) -> h_all (main | masked contiguous)
    pv_kernel<false><<<dim3(17, B_*H_), 256, 0, stream>>>(sc, vT, nullptr, h_all);
    pv_kernel<true ><<<dim3(17 * B_ * M_ * H_), 256, 0, stream>>>(sc, vT, mpk, h_all + (size_t)NS*D_);

    // 8. merged Wp projection + residual (main: x, masked: broadcast xn_f)
    gemm_nt<0,3,0><<<dim3(145,6),512,0,stream>>>(h_all, WpT, bp, x, xn_f, x_all_pre,
        NALL, D_, D_, D_, D_, D_, 1.f, 1, 0,0,0,0,0,0);

    // 9. combined FFN over all 18450 rows (POOL dead now -> t_buf valid)
    ln_kernel<<<NALL, 256, 0, stream>>>(x_all_pre, g2, be2, xn_all, nullptr);
    gemm_nt<1,0,1><<<dim3(145,24),512,0,stream>>>(xn_all, W1T, b1, nullptr, nullptr, t_buf,
        NALL, FF_, D_, D_, D_, FF_, 1.f, 1, 0,0,0,0,0,0);
    gemm_nt<0,1,0><<<dim3(145,6),512,0,stream>>>(t_buf, W2T, b2, x_all_pre, nullptr, out,
        NALL, D_, FF_, FF_, FF_, D_, 1.f, 1, 0,0,0,0,0,0);

    // 10. img_idx as float values
    write_idx<<<1, 16, 0, stream>>>(out + (size_t)NS*D_ + (size_t)NMS*D_);
}